// Round 15
// baseline (70.546 us; speedup 1.0000x reference)
//
#include <hip/hip_runtime.h>
#include <hip/hip_bf16.h>

#define B_   8
#define SQ_  2048
#define SK_  2048
#define D_   128

typedef __attribute__((ext_vector_type(8))) _Float16 f16x8;
typedef __attribute__((ext_vector_type(4))) _Float16 f16x4;
typedef __attribute__((ext_vector_type(4))) float    f32x4;

// Fragment-major layouts (f16), lane l, hi = l>>4, ql = l&15:
//  Qf[b][qt:128][ks:4][l][8] : elem (q = qt*16+ql, d = ks*32+hi*8+j)  PRE-SCALED log2e/8
//  Kf[b][kt:128][ks:4][l][8] : elem (k = kt*16+ql, d = ks*32+hi*8+j)  PRE-SCALED 1/16
//  Vf[b][kt:64][dt:8][l][8]  : elem (k = kt*32+hi*8+j, d = dt*16+ql)   (B-frag for PV)
//  Pf[b][qtl][kt:64][l][8]   : elem (q = qtl*16+ql, k = kt*32+hi*8+j)  (A-frag for PV)
// => S(mfma) = (Q.K) * log2e/128, so exp(QK/128) = exp2(S): one v_exp_f32.
// NOTE (r12): Pf lives in LLC between zred and av — NO nontemporal hints.
// NOTE (r14): zred operands (256KB/block) can never be LDS-staged — per-lane
// loads are correct there; they hit L2 (32x tile reuse).
#define QK_BSTRIDE (128 * 4 * 64 * 8)   // 262144 elems per batch
#define VF_BSTRIDE (64 * 8 * 64 * 8)    // 262144 elems per batch

__device__ __forceinline__ void dma16(const void* g, void* l) {
    __builtin_amdgcn_global_load_lds(
        (const __attribute__((address_space(1))) unsigned int*)g,
        (__attribute__((address_space(3))) unsigned int*)l, 16, 0, 0);
}

__device__ __forceinline__ float fast_exp2(float x) {
#if __has_builtin(__builtin_amdgcn_exp2f)
    return __builtin_amdgcn_exp2f(x);
#else
    return __expf(x * 0.6931471805599453f);
#endif
}

// ---------------------------------------------------------------------------
// prep: blocks 0..511   -> Q,K fp32 -> fragment-major f16 (pre-scaled),
//                          fully-coalesced reads via LDS repack
//       blocks 512..767 -> V fp32 -> PV-B-fragment-major f16
// ---------------------------------------------------------------------------
__global__ __launch_bounds__(256)
void prep(const float* __restrict__ Q, const float* __restrict__ K,
          const float* __restrict__ V,
          _Float16* __restrict__ Qf, _Float16* __restrict__ Kf,
          _Float16* __restrict__ Vf) {
    __shared__ _Float16 T[64][136];
    const int bid = blockIdx.x;
    const int t   = threadIdx.x;
    if (bid < 512) {
        const int tens = bid >> 8;            // 0 = Q, 1 = K
        const float* src = tens ? K : Q;
        _Float16*    dst = tens ? Kf : Qf;
        const float  sc  = tens ? 0.0625f : 0.18033688f;  // 1/16, log2e/8
        const int b  = (bid >> 5) & 7;
        const int rb = bid & 31;              // 64-row block
        const int row = t >> 2, c0 = (t & 3) * 32;
        const float* srow = src + ((size_t)b * 2048 + rb * 64 + row) * 128 + c0;
#pragma unroll
        for (int u = 0; u < 32; u += 4) {
            f32x4 v = *(const f32x4*)(srow + u);
            f16x4 h;
            h[0] = (_Float16)(v[0] * sc); h[1] = (_Float16)(v[1] * sc);
            h[2] = (_Float16)(v[2] * sc); h[3] = (_Float16)(v[3] * sc);
            *(f16x4*)&T[row][c0 + u] = h;
        }
        __syncthreads();
        // 1024 f16x8 chunks in fragment order, contiguous global stores
#pragma unroll
        for (int u = 0; u < 4; ++u) {
            int c  = u * 256 + t;
            int l  = c & 63;
            int ks = (c >> 6) & 3;
            int qt = c >> 8;                  // 0..3
            int hi = l >> 4, ql = l & 15;
            f16x8 r = *(const f16x8*)&T[qt * 16 + ql][ks * 32 + hi * 8];
            *(f16x8*)(dst + ((((size_t)b * 128 + rb * 4 + qt) * 4 + ks) * 64 + l) * 8) = r;
        }
    } else {
        const int vb = bid - 512;             // 0..255
        const int b  = vb >> 5;
        const int kb = vb & 31;
        const int row = t >> 2, c0 = (t & 3) * 32;
        const float* src = V + ((size_t)b * SK_ + kb * 64 + row) * D_ + c0;
#pragma unroll
        for (int u = 0; u < 8; ++u) {
            f32x4 v = *(const f32x4*)(src + u * 4);
            f16x4 h;
            h[0] = (_Float16)v[0]; h[1] = (_Float16)v[1];
            h[2] = (_Float16)v[2]; h[3] = (_Float16)v[3];
            *(f16x4*)&T[row][c0 + u * 4] = h;
        }
        __syncthreads();
#pragma unroll
        for (int u = 0; u < 4; ++u) {
            int s   = u * 256 + t;            // 0..1023
            int l   = s & 63;
            int dt  = (s >> 6) & 7;
            int ktl = s >> 9;                 // 0..1
            int hi  = l >> 4, ql = l & 15;
            f16x8 r;
#pragma unroll
            for (int j = 0; j < 8; ++j) r[j] = T[ktl * 32 + hi * 8 + j][dt * 16 + ql];
            *(f16x8*)(Vf + (((size_t)b * 64 + kb * 2 + ktl) * 8 + dt) * 512 + (size_t)l * 8) = r;
        }
    }
}

// ---------------------------------------------------------------------------
// Phase 1: P_b[q][k] = exp2(S_b) / sum_b exp2(S_b), written for ALL 8
// batches in PV-A-fragment-major layout.
// r15: each block processes TWO consecutive k-tiles (grid (nq/64)*16 = 512
// at nq=2048 -> single full-occupancy pass, Q chunks L1/L2-hot for tile 2).
// ---------------------------------------------------------------------------
__global__ __launch_bounds__(512, 4)
void zred(const _Float16* __restrict__ Qf, const _Float16* __restrict__ Kf,
          _Float16* __restrict__ Pf, int nqt, int qoff16) {
    __shared__ __attribute__((aligned(16))) _Float16 E[8][64][64];  // 64 KB
    const int bid   = blockIdx.x;
    const int qtile = bid >> 4;          // local to chunk
    const int ktp   = bid & 15;          // k-tile PAIR (XCD-spread via bid&7)
    const int b  = threadIdx.x >> 6;
    const int l  = threadIdx.x & 63;
    const int hi = l >> 4, ql = l & 15;

    const _Float16* Qb = Qf + (size_t)b * QK_BSTRIDE;
    const _Float16* Kb = Kf + (size_t)b * QK_BSTRIDE;

    // ktile-independent E-read decode (hoisted)
    const int t    = threadIdx.x;
    const int ktl  = t >> 8;             // 0..1
    const int qq2  = (t >> 6) & 3;       // 0..3
    const int l2   = t & 63;
    const int q_loc  = qq2 * 16 + (l2 & 15);
    const int k0_loc = ktl * 32 + (l2 >> 4) * 8;
    const f16x8* E8  = (const f16x8*)&E[0][0][0];
    const int eidx   = (q_loc << 3) + ((k0_loc >> 3) ^ (q_loc & 7));

#pragma unroll 1
    for (int kt2 = 0; kt2 < 2; ++kt2) {
        const int ktile = ktp * 2 + kt2;

        // swapped S^T = mfma(K, Q): lane holds k = kk*16+hi*4+r, q = qq*16+ql
        f32x4 s[4][4] = {};
        __builtin_amdgcn_s_setprio(1);
#pragma unroll
        for (int ks = 0; ks < 4; ++ks) {
            f16x8 kf[4];
#pragma unroll
            for (int kk = 0; kk < 4; ++kk)
                kf[kk] = *(const f16x8*)(Kb + ((((size_t)ktile * 4 + kk) * 4 + ks) * 64 + l) * 8);
#pragma unroll
            for (int qq = 0; qq < 4; ++qq) {
                f16x8 qv = *(const f16x8*)(Qb + ((((size_t)(qoff16 + qtile * 4 + qq)) * 4 + ks) * 64 + l) * 8);
#pragma unroll
                for (int kk = 0; kk < 4; ++kk)
                    s[kk][qq] = __builtin_amdgcn_mfma_f32_16x16x32_f16(kf[kk], qv, s[kk][qq], 0, 0, 0);
            }
        }
        __builtin_amdgcn_s_setprio(0);

        // E[b][q][k] = exp2(S), 16B-granule XOR swizzle on k-group
        f16x4* E4 = (f16x4*)&E[0][0][0];
#pragma unroll
        for (int kk = 0; kk < 4; ++kk)
#pragma unroll
            for (int qq = 0; qq < 4; ++qq) {
                f16x4 e;
#pragma unroll
                for (int r = 0; r < 4; ++r)
                    e[r] = (_Float16)fast_exp2(s[kk][qq][r]);
                int q = qq * 16 + ql;
                int k = kk * 16 + hi * 4;
                int g16 = ((b * 64 + q) << 3) + ((k >> 3) ^ (q & 7));
                E4[g16 * 2 + ((k >> 2) & 1)] = e;
            }
        __syncthreads();

        // pass 1: z = sum_b e_b
        f16x8 z = E8[eidx];
#pragma unroll
        for (int bb = 1; bb < 8; ++bb) z = z + E8[bb * 512 + eidx];
        float inv[8];
#pragma unroll
        for (int j = 0; j < 8; ++j) inv[j] = __builtin_amdgcn_rcpf((float)z[j]);

        // pass 2: P_b = e_b * inv, coalesced f16x8 store per batch
        const size_t pbase = (((size_t)(qtile * 4 + qq2)) * 64 + (ktile * 2 + ktl)) * 512
                           + (size_t)l2 * 8;
#pragma unroll
        for (int bb = 0; bb < 8; ++bb) {
            f16x8 e = E8[bb * 512 + eidx];
            f16x8 p;
#pragma unroll
            for (int j = 0; j < 8; ++j) p[j] = (_Float16)((float)e[j] * inv[j]);
            *(f16x8*)(Pf + (size_t)bb * nqt * 32768 + pbase) = p;
        }
        __syncthreads();                 // E fully consumed before next tile
    }
}

// ---------------------------------------------------------------------------
// Phase 2: O_b = P_b @ V_b — staged GEMM, global_load_lds, K-STEP 128:
// 3 x 48KB buffers, prefetch distance 2, counted vmcnt(12), single barrier
// per 128-k iteration. Per iter: stage P 16KB + V 32KB = 48 x 1KB DMA chunks.
// grid (nq/64)*8, block 512. Block = (b, 64q); wave = 32q x 32d quadrant.
// ---------------------------------------------------------------------------
__global__ __launch_bounds__(512)
void av(const _Float16* __restrict__ Pf, const _Float16* __restrict__ Vf,
        float* __restrict__ out, int nqt, int qoff) {
    __shared__ __attribute__((aligned(16))) _Float16 lds[3 * 24576];  // 3 x 48KB

    const int bid = blockIdx.x;
    const int b   = bid & 7;             // batch -> XCD pinned (V_b L2-resident)
    const int mt  = bid >> 3;            // 64-q M-tile (chunk-local)
    const int w   = threadIdx.x >> 6;
    const int l   = threadIdx.x & 63;
    const int wq  = w >> 2;              // 0..1
    const int wd  = w & 3;               // 0..3
    const int hi  = l >> 4, ql = l & 15;

    const _Float16* Pb = Pf + (size_t)b * nqt * 32768;
    const _Float16* Vb = Vf + (size_t)b * VF_BSTRIDE;

#define STAGE(bufi, kt4) do {                                                  \
    _Float16* dst0 = (_Float16*)lds + (size_t)(bufi) * 24576;                  \
    _Pragma("unroll")                                                          \
    for (int u = 0; u < 6; ++u) {                                              \
        int c = w * 6 + u;                                                     \
        const _Float16* srcp;                                                  \
        if (c < 16)                                                            \
            srcp = Pb + (((size_t)(mt * 4 + (c >> 2))) * 64 + ((kt4) * 4 + (c & 3))) * 512 + (size_t)l * 8; \
        else {                                                                 \
            int cv = c - 16;                                                   \
            srcp = Vb + (((size_t)((kt4) * 4 + (cv >> 3))) * 8 + (cv & 7)) * 512 + (size_t)l * 8; \
        }                                                                      \
        dma16(srcp, dst0 + c * 512);                                           \
    }                                                                          \
} while (0)

#define MFMA_PHASE(bufi) do {                                                  \
    const _Float16* Bf = (const _Float16*)lds + (size_t)(bufi) * 24576;        \
    _Pragma("unroll")                                                          \
    for (int ktl = 0; ktl < 4; ++ktl) {                                        \
        f16x8 pfr[2], vfr[2];                                                  \
        _Pragma("unroll")                                                      \
        for (int i = 0; i < 2; ++i)                                            \
            pfr[i] = *(const f16x8*)(Bf + ((wq * 2 + i) * 4 + ktl) * 512 + l * 8); \
        _Pragma("unroll")                                                      \
        for (int j = 0; j < 2; ++j)                                            \
            vfr[j] = *(const f16x8*)(Bf + 8192 + (ktl * 8 + wd * 2 + j) * 512 + l * 8); \
        _Pragma("unroll")                                                      \
        for (int i = 0; i < 2; ++i)                                            \
            _Pragma("unroll")                                                  \
            for (int j = 0; j < 2; ++j)                                        \
                acc[i][j] = __builtin_amdgcn_mfma_f32_16x16x32_f16(pfr[i], vfr[j], acc[i][j], 0, 0, 0); \
    }                                                                          \
} while (0)

    f32x4 acc[2][2] = {};
    STAGE(0, 0);
    STAGE(1, 1);
    for (int kt4 = 0; kt4 < 16; ++kt4) {
        // oldest in-flight stage = kt4; at most 2 newer stages (12 chunks/wave)
        if (kt4 <= 13)      asm volatile("s_waitcnt vmcnt(12)" ::: "memory");
        else if (kt4 == 14) asm volatile("s_waitcnt vmcnt(6)" ::: "memory");
        else                asm volatile("s_waitcnt vmcnt(0)" ::: "memory");
        __builtin_amdgcn_s_barrier();          // all waves' stage[kt4] landed
        __builtin_amdgcn_sched_barrier(0);     // no ds_read hoisting above
        if (kt4 < 14) STAGE((kt4 + 2) % 3, kt4 + 2);
        __builtin_amdgcn_s_setprio(1);
        MFMA_PHASE(kt4 % 3);
        __builtin_amdgcn_s_setprio(0);
    }

    // D-layout: q = +hi*4+r, d = +ql ; each output element written once
    const int q0 = qoff + mt * 64 + wq * 32;
#pragma unroll
    for (int i = 0; i < 2; ++i)
#pragma unroll
        for (int j = 0; j < 2; ++j)
#pragma unroll
            for (int r = 0; r < 4; ++r)
                out[((size_t)b * SQ_ + q0 + i * 16 + hi * 4 + r) * D_ + (wd * 2 + j) * 16 + ql]
                    = acc[i][j][r];
#undef STAGE
#undef MFMA_PHASE
}

// ---------------------------------------------------------------------------
extern "C" void kernel_launch(void* const* d_in, const int* in_sizes, int n_in,
                              void* d_out, int out_size, void* d_ws, size_t ws_size,
                              hipStream_t stream) {
    const float* Q = (const float*)d_in[0];
    const float* K = (const float*)d_in[1];
    const float* V = (const float*)d_in[2];
    float* out = (float*)d_out;

    _Float16* Qf = (_Float16*)d_ws;                       // 4 MB
    _Float16* Kf = Qf + (size_t)B_ * QK_BSTRIDE;          // 4 MB
    _Float16* Vf = Kf + (size_t)B_ * QK_BSTRIDE;          // 4 MB
    _Float16* Pf = Vf + (size_t)B_ * VF_BSTRIDE;          // up to 64 MB

    // fit P-chunk (nq q-rows): nq * 8b * 2048k * 2B = nq * 32KB
    size_t used  = (size_t)(12 * 1024 * 1024);
    size_t avail = ws_size > used ? (ws_size - used) / 2 : 0;   // f16 elems
    int nq = 2048;
    while (nq > 64 && (size_t)nq * 16384 > avail) nq >>= 1;
    int nchunks = 2048 / nq;
    int nqt = nq / 16;

    prep<<<768, 256, 0, stream>>>(Q, K, V, Qf, Kf, Vf);

    for (int ci = 0; ci < nchunks; ++ci) {
        int qoff = ci * nq;
        zred<<<(nq / 64) * 16, 512, 0, stream>>>(Qf, Kf, Pf, nqt, qoff >> 4);
        av<<<(nq / 64) * 8, 512, 0, stream>>>(Pf, Vf, out, nqt, qoff);
    }
}

// Round 17
// 67.150 us; speedup vs baseline: 1.0506x; 1.0506x over previous
//
#include <hip/hip_runtime.h>
#include <hip/hip_bf16.h>

#define B_   8
#define SQ_  2048
#define SK_  2048
#define D_   128

typedef __attribute__((ext_vector_type(8))) _Float16 f16x8;
typedef __attribute__((ext_vector_type(4))) _Float16 f16x4;
typedef __attribute__((ext_vector_type(4))) float    f32x4;

// Fragment-major layouts (f16), lane l, hi = l>>4, ql = l&15:
//  Qf[b][qt:128][ks:4][l][8] : elem (q = qt*16+ql, d = ks*32+hi*8+j)  PRE-SCALED log2e/8
//  Kf[b][kt:128][ks:4][l][8] : elem (k = kt*16+ql, d = ks*32+hi*8+j)  PRE-SCALED 1/16
//  Vf[b][kt:64][dt:8][l][8]  : elem (k = kt*32+hi*8+j, d = dt*16+ql)   (B-frag for PV)
//  Pf[b][qtl][kt:64][l][8]   : elem (q = qtl*16+ql, k = kt*32+hi*8+j)  (A-frag for PV)
// => S(mfma) = (Q.K) * log2e/128, so exp(QK/128) = exp2(S): one v_exp_f32.
// NOTE (r12): Pf lives in LLC between zred and av — NO nontemporal hints.
// NOTE (r15): never __syncthreads after P-stores in a loop (drains vmcnt).
// NOTE (r16): 2-buffer distance-1 prefetch REQUIRES a trailing barrier —
// the next ZSTAGE is issued BEFORE the leading barrier, racing slow waves'
// reads of the buffer it overwrites. (3-buffer av needs no trailing barrier.)
#define QK_BSTRIDE (128 * 4 * 64 * 8)   // 262144 elems per batch
#define VF_BSTRIDE (64 * 8 * 64 * 8)    // 262144 elems per batch

__device__ __forceinline__ void dma16(const void* g, void* l) {
    __builtin_amdgcn_global_load_lds(
        (const __attribute__((address_space(1))) unsigned int*)g,
        (__attribute__((address_space(3))) unsigned int*)l, 16, 0, 0);
}

__device__ __forceinline__ float fast_exp2(float x) {
#if __has_builtin(__builtin_amdgcn_exp2f)
    return __builtin_amdgcn_exp2f(x);
#else
    return __expf(x * 0.6931471805599453f);
#endif
}

// ---------------------------------------------------------------------------
// prep: blocks 0..511   -> Q,K fp32 -> fragment-major f16 (pre-scaled)
//       blocks 512..767 -> V fp32 -> PV-B-fragment-major f16
// ---------------------------------------------------------------------------
__global__ __launch_bounds__(256)
void prep(const float* __restrict__ Q, const float* __restrict__ K,
          const float* __restrict__ V,
          _Float16* __restrict__ Qf, _Float16* __restrict__ Kf,
          _Float16* __restrict__ Vf) {
    __shared__ _Float16 T[64][136];
    const int bid = blockIdx.x;
    const int t   = threadIdx.x;
    if (bid < 512) {
        const int tens = bid >> 8;            // 0 = Q, 1 = K
        const float* src = tens ? K : Q;
        _Float16*    dst = tens ? Kf : Qf;
        const float  sc  = tens ? 0.0625f : 0.18033688f;  // 1/16, log2e/8
        const int b  = (bid >> 5) & 7;
        const int rb = bid & 31;              // 64-row block
        const int row = t >> 2, c0 = (t & 3) * 32;
        const float* srow = src + ((size_t)b * 2048 + rb * 64 + row) * 128 + c0;
#pragma unroll
        for (int u = 0; u < 32; u += 4) {
            f32x4 v = *(const f32x4*)(srow + u);
            f16x4 h;
            h[0] = (_Float16)(v[0] * sc); h[1] = (_Float16)(v[1] * sc);
            h[2] = (_Float16)(v[2] * sc); h[3] = (_Float16)(v[3] * sc);
            *(f16x4*)&T[row][c0 + u] = h;
        }
        __syncthreads();
#pragma unroll
        for (int u = 0; u < 4; ++u) {
            int c  = u * 256 + t;
            int l  = c & 63;
            int ks = (c >> 6) & 3;
            int qt = c >> 8;                  // 0..3
            int hi = l >> 4, ql = l & 15;
            f16x8 r = *(const f16x8*)&T[qt * 16 + ql][ks * 32 + hi * 8];
            *(f16x8*)(dst + ((((size_t)b * 128 + rb * 4 + qt) * 4 + ks) * 64 + l) * 8) = r;
        }
    } else {
        const int vb = bid - 512;             // 0..255
        const int b  = vb >> 5;
        const int kb = vb & 31;
        const int row = t >> 2, c0 = (t & 3) * 32;
        const float* src = V + ((size_t)b * SK_ + kb * 64 + row) * D_ + c0;
#pragma unroll
        for (int u = 0; u < 8; ++u) {
            f32x4 v = *(const f32x4*)(src + u * 4);
            f16x4 h;
            h[0] = (_Float16)v[0]; h[1] = (_Float16)v[1];
            h[2] = (_Float16)v[2]; h[3] = (_Float16)v[3];
            *(f16x4*)&T[row][c0 + u * 4] = h;
        }
        __syncthreads();
#pragma unroll
        for (int u = 0; u < 4; ++u) {
            int s   = u * 256 + t;            // 0..1023
            int l   = s & 63;
            int dt  = (s >> 6) & 7;
            int ktl = s >> 9;                 // 0..1
            int hi  = l >> 4, ql = l & 15;
            f16x8 r;
#pragma unroll
            for (int j = 0; j < 8; ++j) r[j] = T[ktl * 32 + hi * 8 + j][dt * 16 + ql];
            *(f16x8*)(Vf + (((size_t)b * 64 + kb * 2 + ktl) * 8 + dt) * 512 + (size_t)l * 8) = r;
        }
    }
}

// ---------------------------------------------------------------------------
// Phase 1 (r17): P_b = exp2(S_b)/sum_b exp2(S_b). Batch-looped, DMA-staged:
// all 8 waves cooperate on one batch per iteration (wave w -> frags
// kk=w>>1, qq=(w&1)*2+{0,1}); Q+K tile (32 KB) double-buffered via
// global_load_lds, counted vmcnt(4). TWO barriers per batch: leading
// (stage landed) + trailing (reads done before next overwrite) — r16 race.
// grid (nq/64)*32, block 512, LDS 128 KB -> 1 block/CU.
// ---------------------------------------------------------------------------
__global__ __launch_bounds__(512)
void zred(const _Float16* __restrict__ Qf, const _Float16* __restrict__ Kf,
          _Float16* __restrict__ Pf, int nqt, int qoff16) {
    __shared__ __attribute__((aligned(16))) _Float16 E[8][64][64];    // 64 KB
    __shared__ __attribute__((aligned(16))) _Float16 SBUF[2][16384];  // 64 KB

    const int bid   = blockIdx.x;
    const int qtile = bid >> 5;          // local to chunk
    const int ktile = bid & 31;
    const int w  = threadIdx.x >> 6;
    const int l  = threadIdx.x & 63;
    const int hi = l >> 4, ql = l & 15;

    // wave w -> output frags (kk, qq0..qq0+1)
    const int kk  = w >> 1;
    const int qq0 = (w & 1) * 2;

    // stage chunks: c<16 Q-frag (qq=c>>2, ks=c&3); c>=16 K-frag (kk, ks)
#define ZSTAGE(bufi, bb) do {                                                  \
    _Float16* dst0 = &SBUF[bufi][0];                                           \
    const _Float16* Qb = Qf + (size_t)(bb) * QK_BSTRIDE;                       \
    const _Float16* Kb = Kf + (size_t)(bb) * QK_BSTRIDE;                       \
    _Pragma("unroll")                                                          \
    for (int u = 0; u < 4; ++u) {                                              \
        int c = w * 4 + u;                                                     \
        const _Float16* srcp;                                                  \
        if (c < 16)                                                            \
            srcp = Qb + ((((size_t)(qoff16 + qtile * 4 + (c >> 2))) * 4 + (c & 3)) * 64 + l) * 8; \
        else                                                                   \
            srcp = Kb + ((((size_t)(ktile * 4 + ((c - 16) >> 2))) * 4 + (c & 3)) * 64 + l) * 8;   \
        dma16(srcp, dst0 + c * 512);                                           \
    }                                                                          \
} while (0)

    f16x4* E4 = (f16x4*)&E[0][0][0];

    ZSTAGE(0, 0);
#pragma unroll 1
    for (int b = 0; b < 8; ++b) {
        if (b < 7) {
            ZSTAGE((b + 1) & 1, b + 1);
            asm volatile("s_waitcnt vmcnt(4)" ::: "memory");  // stage b landed
        } else {
            asm volatile("s_waitcnt vmcnt(0)" ::: "memory");
        }
        __builtin_amdgcn_s_barrier();
        __builtin_amdgcn_sched_barrier(0);
        const _Float16* SB = &SBUF[b & 1][0];

        // swapped S^T = mfma(K, Q): lane holds k = kk*16+hi*4+r, q = qq*16+ql
        f32x4 s0 = {}, s1 = {};
        __builtin_amdgcn_s_setprio(1);
#pragma unroll
        for (int ks = 0; ks < 4; ++ks) {
            f16x8 kf8 = *(const f16x8*)(SB + (16 + kk * 4 + ks) * 512 + l * 8);
            f16x8 q0  = *(const f16x8*)(SB + ((qq0 + 0) * 4 + ks) * 512 + l * 8);
            f16x8 q1  = *(const f16x8*)(SB + ((qq0 + 1) * 4 + ks) * 512 + l * 8);
            s0 = __builtin_amdgcn_mfma_f32_16x16x32_f16(kf8, q0, s0, 0, 0, 0);
            s1 = __builtin_amdgcn_mfma_f32_16x16x32_f16(kf8, q1, s1, 0, 0, 0);
        }
        __builtin_amdgcn_s_setprio(0);

        // E[b] = exp2(S), 16B-granule XOR swizzle on k-group
#pragma unroll
        for (int i = 0; i < 2; ++i) {
            f32x4 sv = i ? s1 : s0;
            f16x4 e;
#pragma unroll
            for (int r = 0; r < 4; ++r) e[r] = (_Float16)fast_exp2(sv[r]);
            int q = (qq0 + i) * 16 + ql;
            int k = kk * 16 + hi * 4;
            int g16 = ((b * 64 + q) << 3) + ((k >> 3) ^ (q & 7));
            E4[g16 * 2 + ((k >> 2) & 1)] = e;
        }
        // trailing barrier: all waves' SB reads done before next ZSTAGE
        // overwrites this buffer (raw s_barrier — does NOT drain vmcnt)
        __builtin_amdgcn_s_barrier();
    }
    __syncthreads();                     // all E ds_writes visible

    // thread -> PV-A-frag slot: (ktl, qq2, lane)
    const int t    = threadIdx.x;
    const int ktl  = t >> 8;             // 0..1
    const int qq2  = (t >> 6) & 3;       // 0..3
    const int l2   = t & 63;
    const int q_loc  = qq2 * 16 + (l2 & 15);
    const int k0_loc = ktl * 32 + (l2 >> 4) * 8;
    const f16x8* E8  = (const f16x8*)&E[0][0][0];
    const int eidx   = (q_loc << 3) + ((k0_loc >> 3) ^ (q_loc & 7));

    // pass 1: z = sum_b e_b
    f16x8 z = E8[eidx];
#pragma unroll
    for (int bb = 1; bb < 8; ++bb) z = z + E8[bb * 512 + eidx];
    float inv[8];
#pragma unroll
    for (int j = 0; j < 8; ++j) inv[j] = __builtin_amdgcn_rcpf((float)z[j]);

    // pass 2: P_b = e_b * inv, coalesced f16x8 store per batch
    const size_t pbase = (((size_t)(qtile * 4 + qq2)) * 64 + (ktile * 2 + ktl)) * 512 + (size_t)l2 * 8;
#pragma unroll
    for (int bb = 0; bb < 8; ++bb) {
        f16x8 e = E8[bb * 512 + eidx];
        f16x8 p;
#pragma unroll
        for (int j = 0; j < 8; ++j) p[j] = (_Float16)((float)e[j] * inv[j]);
        *(f16x8*)(Pf + (size_t)bb * nqt * 32768 + pbase) = p;
    }
#undef ZSTAGE
}

// ---------------------------------------------------------------------------
// Phase 2: O_b = P_b @ V_b — staged GEMM, global_load_lds, K-STEP 128:
// 3 x 48KB buffers, prefetch distance 2, counted vmcnt(12), single barrier
// per 128-k iteration. Per iter: stage P 16KB + V 32KB = 48 x 1KB DMA chunks.
// grid (nq/64)*8, block 512. Block = (b, 64q); wave = 32q x 32d quadrant.
// ---------------------------------------------------------------------------
__global__ __launch_bounds__(512)
void av(const _Float16* __restrict__ Pf, const _Float16* __restrict__ Vf,
        float* __restrict__ out, int nqt, int qoff) {
    __shared__ __attribute__((aligned(16))) _Float16 lds[3 * 24576];  // 3 x 48KB

    const int bid = blockIdx.x;
    const int b   = bid & 7;             // batch -> XCD pinned (V_b L2-resident)
    const int mt  = bid >> 3;            // 64-q M-tile (chunk-local)
    const int w   = threadIdx.x >> 6;
    const int l   = threadIdx.x & 63;
    const int wq  = w >> 2;              // 0..1
    const int wd  = w & 3;               // 0..3
    const int hi  = l >> 4, ql = l & 15;

    const _Float16* Pb = Pf + (size_t)b * nqt * 32768;
    const _Float16* Vb = Vf + (size_t)b * VF_BSTRIDE;

#define STAGE(bufi, kt4) do {                                                  \
    _Float16* dst0 = (_Float16*)lds + (size_t)(bufi) * 24576;                  \
    _Pragma("unroll")                                                          \
    for (int u = 0; u < 6; ++u) {                                              \
        int c = w * 6 + u;                                                     \
        const _Float16* srcp;                                                  \
        if (c < 16)                                                            \
            srcp = Pb + (((size_t)(mt * 4 + (c >> 2))) * 64 + ((kt4) * 4 + (c & 3))) * 512 + (size_t)l * 8; \
        else {                                                                 \
            int cv = c - 16;                                                   \
            srcp = Vb + (((size_t)((kt4) * 4 + (cv >> 3))) * 8 + (cv & 7)) * 512 + (size_t)l * 8; \
        }                                                                      \
        dma16(srcp, dst0 + c * 512);                                           \
    }                                                                          \
} while (0)

#define MFMA_PHASE(bufi) do {                                                  \
    const _Float16* Bf = (const _Float16*)lds + (size_t)(bufi) * 24576;        \
    _Pragma("unroll")                                                          \
    for (int ktl = 0; ktl < 4; ++ktl) {                                        \
        f16x8 pfr[2], vfr[2];                                                  \
        _Pragma("unroll")                                                      \
        for (int i = 0; i < 2; ++i)                                            \
            pfr[i] = *(const f16x8*)(Bf + ((wq * 2 + i) * 4 + ktl) * 512 + l * 8); \
        _Pragma("unroll")                                                      \
        for (int j = 0; j < 2; ++j)                                            \
            vfr[j] = *(const f16x8*)(Bf + 8192 + (ktl * 8 + wd * 2 + j) * 512 + l * 8); \
        _Pragma("unroll")                                                      \
        for (int i = 0; i < 2; ++i)                                            \
            _Pragma("unroll")                                                  \
            for (int j = 0; j < 2; ++j)                                        \
                acc[i][j] = __builtin_amdgcn_mfma_f32_16x16x32_f16(pfr[i], vfr[j], acc[i][j], 0, 0, 0); \
    }                                                                          \
} while (0)

    f32x4 acc[2][2] = {};
    STAGE(0, 0);
    STAGE(1, 1);
    for (int kt4 = 0; kt4 < 16; ++kt4) {
        // oldest in-flight stage = kt4; at most 2 newer stages (12 chunks/wave)
        if (kt4 <= 13)      asm volatile("s_waitcnt vmcnt(12)" ::: "memory");
        else if (kt4 == 14) asm volatile("s_waitcnt vmcnt(6)" ::: "memory");
        else                asm volatile("s_waitcnt vmcnt(0)" ::: "memory");
        __builtin_amdgcn_s_barrier();          // all waves' stage[kt4] landed
        __builtin_amdgcn_sched_barrier(0);     // no ds_read hoisting above
        if (kt4 < 14) STAGE((kt4 + 2) % 3, kt4 + 2);
        __builtin_amdgcn_s_setprio(1);
        MFMA_PHASE(kt4 % 3);
        __builtin_amdgcn_s_setprio(0);
    }

    // D-layout: q = +hi*4+r, d = +ql ; each output element written once
    const int q0 = qoff + mt * 64 + wq * 32;
#pragma unroll
    for (int i = 0; i < 2; ++i)
#pragma unroll
        for (int j = 0; j < 2; ++j)
#pragma unroll
            for (int r = 0; r < 4; ++r)
                out[((size_t)b * SQ_ + q0 + i * 16 + hi * 4 + r) * D_ + (wd * 2 + j) * 16 + ql]
                    = acc[i][j][r];
#undef STAGE
#undef MFMA_PHASE
}

// ---------------------------------------------------------------------------
extern "C" void kernel_launch(void* const* d_in, const int* in_sizes, int n_in,
                              void* d_out, int out_size, void* d_ws, size_t ws_size,
                              hipStream_t stream) {
    const float* Q = (const float*)d_in[0];
    const float* K = (const float*)d_in[1];
    const float* V = (const float*)d_in[2];
    float* out = (float*)d_out;

    _Float16* Qf = (_Float16*)d_ws;                       // 4 MB
    _Float16* Kf = Qf + (size_t)B_ * QK_BSTRIDE;          // 4 MB
    _Float16* Vf = Kf + (size_t)B_ * QK_BSTRIDE;          // 4 MB
    _Float16* Pf = Vf + (size_t)B_ * VF_BSTRIDE;          // up to 64 MB

    // fit P-chunk (nq q-rows): nq * 8b * 2048k * 2B = nq * 32KB
    size_t used  = (size_t)(12 * 1024 * 1024);
    size_t avail = ws_size > used ? (ws_size - used) / 2 : 0;   // f16 elems
    int nq = 2048;
    while (nq > 64 && (size_t)nq * 16384 > avail) nq >>= 1;
    int nchunks = 2048 / nq;
    int nqt = nq / 16;

    prep<<<768, 256, 0, stream>>>(Q, K, V, Qf, Kf, Vf);

    for (int ci = 0; ci < nchunks; ++ci) {
        int qoff = ci * nq;
        zred<<<(nq / 64) * 32, 512, 0, stream>>>(Qf, Kf, Pf, nqt, qoff >> 4);
        av<<<(nq / 64) * 8, 512, 0, stream>>>(Pf, Vf, out, nqt, qoff);
    }
}

// Round 18
// 57.053 us; speedup vs baseline: 1.2365x; 1.1770x over previous
//
#include <hip/hip_runtime.h>
#include <hip/hip_bf16.h>

#define B_   8
#define SQ_  2048
#define SK_  2048
#define D_   128

typedef __attribute__((ext_vector_type(8))) _Float16 f16x8;
typedef __attribute__((ext_vector_type(4))) _Float16 f16x4;
typedef __attribute__((ext_vector_type(4))) float    f32x4;

// Fragment-major layouts (f16), lane l, hi = l>>4, ql = l&15:
//  Qf[b][qt:128][ks:4][l][8] : elem (q = qt*16+ql, d = ks*32+hi*8+j)  PRE-SCALED log2e/8
//  Kf[b][kt:128][ks:4][l][8] : elem (k = kt*16+ql, d = ks*32+hi*8+j)  PRE-SCALED 1/16
//  Vf[b][kt:64][dt:8][l][8]  : elem (k = kt*32+hi*8+j, d = dt*16+ql)   (B-frag for PV)
//  Pf[b][qtl][kt:64][l][8]   : elem (q = qtl*16+ql, k = kt*32+hi*8+j)  (A-frag for PV)
// => S(mfma) = (Q.K) * log2e/128, so exp(QK/128) = exp2(S): one v_exp_f32.
// SESSION LESSONS BAKED IN:
//  r12: Pf lives in LLC between zred and av — NO nontemporal hints.
//  r15: no __syncthreads between P-stores and more work (drains vmcnt).
//  r14-r17: zred per-lane loads are L2-hot and TLP-hidden at 2 blocks/CU;
//           every DMA-staging/fusion variant of zred lost occupancy or raced.
#define QK_BSTRIDE (128 * 4 * 64 * 8)   // 262144 elems per batch
#define VF_BSTRIDE (64 * 8 * 64 * 8)    // 262144 elems per batch

__device__ __forceinline__ void dma16(const void* g, void* l) {
    __builtin_amdgcn_global_load_lds(
        (const __attribute__((address_space(1))) unsigned int*)g,
        (__attribute__((address_space(3))) unsigned int*)l, 16, 0, 0);
}

__device__ __forceinline__ float fast_exp2(float x) {
#if __has_builtin(__builtin_amdgcn_exp2f)
    return __builtin_amdgcn_exp2f(x);
#else
    return __expf(x * 0.6931471805599453f);
#endif
}

// ---------------------------------------------------------------------------
// prep: blocks 0..511   -> Q,K fp32 -> fragment-major f16 (pre-scaled),
//                          fully-coalesced reads via LDS repack
//       blocks 512..767 -> V fp32 -> PV-B-fragment-major f16
// ---------------------------------------------------------------------------
__global__ __launch_bounds__(256)
void prep(const float* __restrict__ Q, const float* __restrict__ K,
          const float* __restrict__ V,
          _Float16* __restrict__ Qf, _Float16* __restrict__ Kf,
          _Float16* __restrict__ Vf) {
    __shared__ _Float16 T[64][136];
    const int bid = blockIdx.x;
    const int t   = threadIdx.x;
    if (bid < 512) {
        const int tens = bid >> 8;            // 0 = Q, 1 = K
        const float* src = tens ? K : Q;
        _Float16*    dst = tens ? Kf : Qf;
        const float  sc  = tens ? 0.0625f : 0.18033688f;  // 1/16, log2e/8
        const int b  = (bid >> 5) & 7;
        const int rb = bid & 31;              // 64-row block
        const int row = t >> 2, c0 = (t & 3) * 32;
        const float* srow = src + ((size_t)b * 2048 + rb * 64 + row) * 128 + c0;
#pragma unroll
        for (int u = 0; u < 32; u += 4) {
            f32x4 v = *(const f32x4*)(srow + u);
            f16x4 h;
            h[0] = (_Float16)(v[0] * sc); h[1] = (_Float16)(v[1] * sc);
            h[2] = (_Float16)(v[2] * sc); h[3] = (_Float16)(v[3] * sc);
            *(f16x4*)&T[row][c0 + u] = h;
        }
        __syncthreads();
        // 1024 f16x8 chunks in fragment order, contiguous global stores
#pragma unroll
        for (int u = 0; u < 4; ++u) {
            int c  = u * 256 + t;
            int l  = c & 63;
            int ks = (c >> 6) & 3;
            int qt = c >> 8;                  // 0..3
            int hi = l >> 4, ql = l & 15;
            f16x8 r = *(const f16x8*)&T[qt * 16 + ql][ks * 32 + hi * 8];
            *(f16x8*)(dst + ((((size_t)b * 128 + rb * 4 + qt) * 4 + ks) * 64 + l) * 8) = r;
        }
    } else {
        const int vb = bid - 512;             // 0..255
        const int b  = vb >> 5;
        const int kb = vb & 31;
        const int row = t >> 2, c0 = (t & 3) * 32;
        const float* src = V + ((size_t)b * SK_ + kb * 64 + row) * D_ + c0;
#pragma unroll
        for (int u = 0; u < 8; ++u) {
            f32x4 v = *(const f32x4*)(src + u * 4);
            f16x4 h;
            h[0] = (_Float16)v[0]; h[1] = (_Float16)v[1];
            h[2] = (_Float16)v[2]; h[3] = (_Float16)v[3];
            *(f16x4*)&T[row][c0 + u * 4] = h;
        }
        __syncthreads();
#pragma unroll
        for (int u = 0; u < 4; ++u) {
            int s   = u * 256 + t;            // 0..1023
            int l   = s & 63;
            int dt  = (s >> 6) & 7;
            int ktl = s >> 9;                 // 0..1
            int hi  = l >> 4, ql = l & 15;
            f16x8 r;
#pragma unroll
            for (int j = 0; j < 8; ++j) r[j] = T[ktl * 32 + hi * 8 + j][dt * 16 + ql];
            *(f16x8*)(Vf + (((size_t)b * 64 + kb * 2 + ktl) * 8 + dt) * 512 + (size_t)l * 8) = r;
        }
    }
}

// ---------------------------------------------------------------------------
// Phase 1: P_b[q][k] = exp2(S_b) / sum_b exp2(S_b), written for ALL 8
// batches in PV-A-fragment-major layout. grid (nq/64)*32, block 512.
// Per-lane operand loads (L2-hot, 32x tile reuse), 2 blocks/CU.
// ---------------------------------------------------------------------------
__global__ __launch_bounds__(512, 4)
void zred(const _Float16* __restrict__ Qf, const _Float16* __restrict__ Kf,
          _Float16* __restrict__ Pf, int nqt, int qoff16) {
    __shared__ __attribute__((aligned(16))) _Float16 E[8][64][64];  // 64 KB
    const int bid   = blockIdx.x;
    const int qtile = bid >> 5;          // local to chunk
    const int ktile = bid & 31;
    const int b  = threadIdx.x >> 6;
    const int l  = threadIdx.x & 63;
    const int hi = l >> 4, ql = l & 15;

    const _Float16* Qb = Qf + (size_t)b * QK_BSTRIDE;
    const _Float16* Kb = Kf + (size_t)b * QK_BSTRIDE;

    // swapped S^T = mfma(K, Q): lane holds k = kk*16+hi*4+r, q = qq*16+ql
    f32x4 s[4][4] = {};
    __builtin_amdgcn_s_setprio(1);
#pragma unroll
    for (int ks = 0; ks < 4; ++ks) {
        f16x8 kf[4];
#pragma unroll
        for (int kk = 0; kk < 4; ++kk)
            kf[kk] = *(const f16x8*)(Kb + ((((size_t)ktile * 4 + kk) * 4 + ks) * 64 + l) * 8);
#pragma unroll
        for (int qq = 0; qq < 4; ++qq) {
            f16x8 qv = *(const f16x8*)(Qb + ((((size_t)(qoff16 + qtile * 4 + qq)) * 4 + ks) * 64 + l) * 8);
#pragma unroll
            for (int kk = 0; kk < 4; ++kk)
                s[kk][qq] = __builtin_amdgcn_mfma_f32_16x16x32_f16(kf[kk], qv, s[kk][qq], 0, 0, 0);
        }
    }
    __builtin_amdgcn_s_setprio(0);

    // E[b][q][k] = exp2(S), 16B-granule XOR swizzle on k-group
    f16x4* E4 = (f16x4*)&E[0][0][0];
#pragma unroll
    for (int kk = 0; kk < 4; ++kk)
#pragma unroll
        for (int qq = 0; qq < 4; ++qq) {
            f16x4 e;
#pragma unroll
            for (int r = 0; r < 4; ++r)
                e[r] = (_Float16)fast_exp2(s[kk][qq][r]);
            int q = qq * 16 + ql;
            int k = kk * 16 + hi * 4;
            int g16 = ((b * 64 + q) << 3) + ((k >> 3) ^ (q & 7));
            E4[g16 * 2 + ((k >> 2) & 1)] = e;
        }
    __syncthreads();

    // thread -> PV-A-frag slot: (ktl, qq2, lane)
    const int t    = threadIdx.x;
    const int ktl  = t >> 8;             // 0..1
    const int qq2  = (t >> 6) & 3;       // 0..3
    const int l2   = t & 63;
    const int hi2  = l2 >> 4, ql2 = l2 & 15;
    const int q_loc  = qq2 * 16 + ql2;
    const int k0_loc = ktl * 32 + hi2 * 8;
    const f16x8* E8  = (const f16x8*)&E[0][0][0];
    const int eidx   = (q_loc << 3) + ((k0_loc >> 3) ^ (q_loc & 7));

    // pass 1: z = sum_b e_b
    f16x8 z = E8[eidx];
#pragma unroll
    for (int bb = 1; bb < 8; ++bb) z = z + E8[bb * 512 + eidx];
    float inv[8];
#pragma unroll
    for (int j = 0; j < 8; ++j) inv[j] = __builtin_amdgcn_rcpf((float)z[j]);

    // pass 2: P_b = e_b * inv, coalesced f16x8 store per batch
    const size_t pbase = (((size_t)(qtile * 4 + qq2)) * 64 + (ktile * 2 + ktl)) * 512 + (size_t)l2 * 8;
#pragma unroll
    for (int bb = 0; bb < 8; ++bb) {
        f16x8 e = E8[bb * 512 + eidx];
        f16x8 p;
#pragma unroll
        for (int j = 0; j < 8; ++j) p[j] = (_Float16)((float)e[j] * inv[j]);
        *(f16x8*)(Pf + (size_t)bb * nqt * 32768 + pbase) = p;
    }
}

// ---------------------------------------------------------------------------
// Phase 2: O_b = P_b @ V_b — staged GEMM, global_load_lds, K-STEP 128:
// 3 x 48KB buffers, prefetch distance 2, counted vmcnt(12), single barrier
// per 128-k iteration. Per iter: stage P 16KB + V 32KB = 48 x 1KB DMA chunks.
// Overwrite safety: STAGE(kt4+2) -> buf[(kt4-1)%3], whose reads were consumed
// by MFMA(kt4-1) before every wave reached barrier_kt4 (program order + lgkm).
// grid (nq/64)*8, block 512. Block = (b, 64q); wave = 32q x 32d quadrant.
// ---------------------------------------------------------------------------
__global__ __launch_bounds__(512)
void av(const _Float16* __restrict__ Pf, const _Float16* __restrict__ Vf,
        float* __restrict__ out, int nqt, int qoff) {
    __shared__ __attribute__((aligned(16))) _Float16 lds[3 * 24576];  // 3 x 48KB

    const int bid = blockIdx.x;
    const int b   = bid & 7;             // batch -> XCD pinned (V_b L2-resident)
    const int mt  = bid >> 3;            // 64-q M-tile (chunk-local)
    const int w   = threadIdx.x >> 6;
    const int l   = threadIdx.x & 63;
    const int wq  = w >> 2;              // 0..1
    const int wd  = w & 3;               // 0..3
    const int hi  = l >> 4, ql = l & 15;

    const _Float16* Pb = Pf + (size_t)b * nqt * 32768;
    const _Float16* Vb = Vf + (size_t)b * VF_BSTRIDE;

#define STAGE(bufi, kt4) do {                                                  \
    _Float16* dst0 = (_Float16*)lds + (size_t)(bufi) * 24576;                  \
    _Pragma("unroll")                                                          \
    for (int u = 0; u < 6; ++u) {                                              \
        int c = w * 6 + u;                                                     \
        const _Float16* srcp;                                                  \
        if (c < 16)                                                            \
            srcp = Pb + (((size_t)(mt * 4 + (c >> 2))) * 64 + ((kt4) * 4 + (c & 3))) * 512 + (size_t)l * 8; \
        else {                                                                 \
            int cv = c - 16;                                                   \
            srcp = Vb + (((size_t)((kt4) * 4 + (cv >> 3))) * 8 + (cv & 7)) * 512 + (size_t)l * 8; \
        }                                                                      \
        dma16(srcp, dst0 + c * 512);                                           \
    }                                                                          \
} while (0)

#define MFMA_PHASE(bufi) do {                                                  \
    const _Float16* Bf = (const _Float16*)lds + (size_t)(bufi) * 24576;        \
    _Pragma("unroll")                                                          \
    for (int ktl = 0; ktl < 4; ++ktl) {                                        \
        f16x8 pfr[2], vfr[2];                                                  \
        _Pragma("unroll")                                                      \
        for (int i = 0; i < 2; ++i)                                            \
            pfr[i] = *(const f16x8*)(Bf + ((wq * 2 + i) * 4 + ktl) * 512 + l * 8); \
        _Pragma("unroll")                                                      \
        for (int j = 0; j < 2; ++j)                                            \
            vfr[j] = *(const f16x8*)(Bf + 8192 + (ktl * 8 + wd * 2 + j) * 512 + l * 8); \
        _Pragma("unroll")                                                      \
        for (int i = 0; i < 2; ++i)                                            \
            _Pragma("unroll")                                                  \
            for (int j = 0; j < 2; ++j)                                        \
                acc[i][j] = __builtin_amdgcn_mfma_f32_16x16x32_f16(pfr[i], vfr[j], acc[i][j], 0, 0, 0); \
    }                                                                          \
} while (0)

    f32x4 acc[2][2] = {};
    STAGE(0, 0);
    STAGE(1, 1);
    for (int kt4 = 0; kt4 < 16; ++kt4) {
        // oldest in-flight stage = kt4; at most 2 newer stages (12 chunks/wave)
        if (kt4 <= 13)      asm volatile("s_waitcnt vmcnt(12)" ::: "memory");
        else if (kt4 == 14) asm volatile("s_waitcnt vmcnt(6)" ::: "memory");
        else                asm volatile("s_waitcnt vmcnt(0)" ::: "memory");
        __builtin_amdgcn_s_barrier();          // all waves' stage[kt4] landed
        __builtin_amdgcn_sched_barrier(0);     // no ds_read hoisting above
        if (kt4 < 14) STAGE((kt4 + 2) % 3, kt4 + 2);
        __builtin_amdgcn_s_setprio(1);
        MFMA_PHASE(kt4 % 3);
        __builtin_amdgcn_s_setprio(0);
    }

    // D-layout: q = +hi*4+r, d = +ql ; each output element written once
    const int q0 = qoff + mt * 64 + wq * 32;
#pragma unroll
    for (int i = 0; i < 2; ++i)
#pragma unroll
        for (int j = 0; j < 2; ++j)
#pragma unroll
            for (int r = 0; r < 4; ++r)
                out[((size_t)b * SQ_ + q0 + i * 16 + hi * 4 + r) * D_ + (wd * 2 + j) * 16 + ql]
                    = acc[i][j][r];
#undef STAGE
#undef MFMA_PHASE
}

// ---------------------------------------------------------------------------
extern "C" void kernel_launch(void* const* d_in, const int* in_sizes, int n_in,
                              void* d_out, int out_size, void* d_ws, size_t ws_size,
                              hipStream_t stream) {
    const float* Q = (const float*)d_in[0];
    const float* K = (const float*)d_in[1];
    const float* V = (const float*)d_in[2];
    float* out = (float*)d_out;

    _Float16* Qf = (_Float16*)d_ws;                       // 4 MB
    _Float16* Kf = Qf + (size_t)B_ * QK_BSTRIDE;          // 4 MB
    _Float16* Vf = Kf + (size_t)B_ * QK_BSTRIDE;          // 4 MB
    _Float16* Pf = Vf + (size_t)B_ * VF_BSTRIDE;          // up to 64 MB

    // fit P-chunk (nq q-rows): nq * 8b * 2048k * 2B = nq * 32KB
    size_t used  = (size_t)(12 * 1024 * 1024);
    size_t avail = ws_size > used ? (ws_size - used) / 2 : 0;   // f16 elems
    int nq = 2048;
    while (nq > 64 && (size_t)nq * 16384 > avail) nq >>= 1;
    int nchunks = 2048 / nq;
    int nqt = nq / 16;

    prep<<<768, 256, 0, stream>>>(Q, K, V, Qf, Kf, Vf);

    for (int ci = 0; ci < nchunks; ++ci) {
        int qoff = ci * nq;
        zred<<<(nq / 64) * 32, 512, 0, stream>>>(Qf, Kf, Pf, nqt, qoff >> 4);
        av<<<(nq / 64) * 8, 512, 0, stream>>>(Pf, Vf, out, nqt, qoff);
    }
}